// Round 14
// baseline (455.286 us; speedup 1.0000x reference)
//
#include <hip/hip_runtime.h>
#include <hip/hip_bf16.h>

typedef __attribute__((ext_vector_type(8))) __bf16 bf16x8;
typedef __attribute__((ext_vector_type(4))) __bf16 bf16x4;
typedef __attribute__((ext_vector_type(4))) float f32x4;
typedef __attribute__((ext_vector_type(4))) unsigned int uintx4;
typedef __attribute__((ext_vector_type(2))) unsigned int uintx2;

__device__ __forceinline__ unsigned short f2bf(float f) {
  __bf16 h = (__bf16)f;
  return __builtin_bit_cast(unsigned short, h);
}
__device__ __forceinline__ float bf2f(unsigned short u) {
  unsigned int x = ((unsigned int)u) << 16;
  return __builtin_bit_cast(float, x);
}
__device__ __forceinline__ bf16x8 ld_frag(const unsigned short* p) {
  return __builtin_bit_cast(bf16x8, *reinterpret_cast<const uintx4*>(p));
}
__device__ __forceinline__ uintx2 cvt4(float4 v) {
  bf16x4 h = { (__bf16)v.x, (__bf16)v.y, (__bf16)v.z, (__bf16)v.w };
  return __builtin_bit_cast(uintx2, h);
}
// async global->LDS, 16B per lane; lds dest must be wave-uniform base
__device__ __forceinline__ void gload16(const unsigned short* g, unsigned short* l) {
  __builtin_amdgcn_global_load_lds(
      (const __attribute__((address_space(1))) void*)g,
      (__attribute__((address_space(3))) void*)l, 16, 0, 0);
}

__device__ __forceinline__ void cvt8(const float* in, unsigned short* out, int gid) {
  const float4* p = reinterpret_cast<const float4*>(in) + (size_t)gid * 2;
  float4 a = p[0], b = p[1];
  uintx2 lo = cvt4(a), hi = cvt4(b);
  uintx4 o = { lo[0], lo[1], hi[0], hi[1] };
  *(reinterpret_cast<uintx4*>(out) + gid) = o;
}

// rope 4 adjacent (even,odd) pairs held in 8 bf16 shorts; cs packed as
// (cos_i, sin_i, cos_{i+1}, sin_{i+1}) float4s
__device__ __forceinline__ void rope8(unsigned short* sh, float4 c0, float4 c1) {
  const float cs[4] = { c0.x, c0.z, c1.x, c1.z };
  const float sn[4] = { c0.y, c0.w, c1.y, c1.w };
  #pragma unroll
  for (int p = 0; p < 4; ++p) {
    float x1 = bf2f(sh[2 * p]), x2 = bf2f(sh[2 * p + 1]);
    sh[2 * p]     = f2bf(x1 * cs[p] - x2 * sn[p]);
    sh[2 * p + 1] = f2bf(x1 * sn[p] + x2 * cs[p]);
  }
}

// 4x4 transpose within each l15-quad (lanes base..base+3):
// input v[j] = row s0+j at this lane's column; output o[p] = row s0+(lane&3)
// at column (quadbase + p).  Verified: requester (g,e) pulls acc[e] of
// provider (g,(e+r)&3) into slot (e+r)&3.
__device__ __forceinline__ void xpose4(const float* v, float* o, int lane) {
  const int e = lane & 3;
  const int base = lane & ~3;
  #pragma unroll
  for (int r = 0; r < 4; ++r) {
    const int slot = (e + r) & 3;
    o[slot] = __shfl(v[(e - r) & 3], base + slot);
  }
}

// ---------------------------------------------------------------------------
// Fused prep: cvt x (8192 blocks) + cvt w_qkv (6144 blocks) + rope table (512)
__global__ __launch_bounds__(256)
void prep(const float* __restrict__ x, unsigned short* __restrict__ xb,
          const float* __restrict__ wqkv, unsigned short* __restrict__ wqkvb,
          float2* __restrict__ tab) {
  const int bid = blockIdx.x, tid = threadIdx.x;
  if (bid < 8192) {
    cvt8(x, xb, bid * 256 + tid);
  } else if (bid < 14336) {
    cvt8(wqkv, wqkvb, (bid - 8192) * 256 + tid);
  } else {
    int gid = (bid - 14336) * 256 + tid;   // 131072 total
    int i = gid & 63, s = gid >> 6;
    double inv = pow(10000.0, -(double)i / 64.0);
    double ang = (double)s * inv;
    tab[gid] = make_float2((float)cos(ang), (float)sin(ang));
  }
}

// fp32 -> bf16 bulk convert, 8 elems/thread
__global__ __launch_bounds__(256)
void cvt_bf16(const float* __restrict__ in, unsigned short* __restrict__ out, int n8) {
  int gid = blockIdx.x * 256 + threadIdx.x;
  if (gid >= n8) return;
  cvt8(in, out, gid);
}

// ---------------------------------------------------------------------------
// 8-phase GEMM C[M][N] = A[M][K] @ B[N][K]^T, bf16 in (R8-proven map, 888 TF).
// BM=BN=256, BK=64, 512 thr (8 waves 2Mx4N), per-wave 128x64 out.
// Bijective XCD swizzle (nwg % 8 == 0). Epilogue: 4x4 shfl transpose ->
// packed stores (float4 for C, bf16x4 for q/k) instead of scalar scatter.
template<int EPI>
__global__ __launch_bounds__(512, 1)
void gemm8(const unsigned short* __restrict__ A, const unsigned short* __restrict__ B,
           float* __restrict__ C, unsigned short* __restrict__ qb,
           unsigned short* __restrict__ kb, unsigned short* __restrict__ vtb,
           int M, int N, int K, int nbx) {
  __shared__ unsigned short Al[2][256 * 64];   // 64 KiB
  __shared__ unsigned short Bl[2][256 * 64];   // 64 KiB
  const int nwg = gridDim.x, bid = blockIdx.x;
  const int swz = (bid & 7) * (nwg >> 3) + (bid >> 3);
  const int n0 = (swz % nbx) * 256, m0 = (swz / nbx) * 256;
  const int tid = threadIdx.x, lane = tid & 63, w = tid >> 6;
  const int wr = w >> 2, wc = w & 3, l15 = lane & 15, l4 = lane >> 4;
  const int NT = K >> 6;

  auto stage_half = [&](const unsigned short* src, int gr0, unsigned short* ldsb, int kt) {
    #pragma unroll
    for (int i = 0; i < 2; ++i) {
      const int rb = (w * 2 + i) * 8;                 // wave-uniform row base
      const int R = rb + (lane >> 3);
      const int cs = ((lane & 7) * 8) ^ ((R & 7) << 3);  // pre-swizzled src col
      gload16(&src[(size_t)(gr0 + R) * K + kt + cs], &ldsb[rb * 64]);
    }
  };
  auto sp_a0b0 = [&](int J) {   // halves {Am0, Bn0} of tile J
    const int buf = J & 1, kt = J * 64;
    stage_half(A, m0, &Al[buf][0], kt);
    stage_half(B, n0, &Bl[buf][0], kt);
  };
  auto sp_b1a1 = [&](int J) {   // halves {Bn1, Am1} of tile J
    const int buf = J & 1, kt = J * 64;
    stage_half(B, n0 + 128, &Bl[buf][128 * 64], kt);
    stage_half(A, m0 + 128, &Al[buf][128 * 64], kt);
  };

  f32x4 acc[8][4];
  const f32x4 z = {0.f, 0.f, 0.f, 0.f};
  #pragma unroll
  for (int mi = 0; mi < 8; ++mi)
    #pragma unroll
    for (int ni = 0; ni < 4; ++ni) acc[mi][ni] = z;

  bf16x8 aF[4][2], bF[4][2];
  auto ldA = [&](int buf, int mh) {
    #pragma unroll
    for (int i = 0; i < 4; ++i) {
      const int R = wr * 128 + (mh * 4 + i) * 16 + l15;
      #pragma unroll
      for (int kk = 0; kk < 2; ++kk)
        aF[i][kk] = ld_frag(&Al[buf][R * 64 + ((kk * 32 + l4 * 8) ^ ((R & 7) << 3))]);
    }
  };
  auto ldB = [&](int buf, int nh) {
    #pragma unroll
    for (int i = 0; i < 2; ++i) {
      const int R = wc * 64 + (nh * 2 + i) * 16 + l15;
      #pragma unroll
      for (int kk = 0; kk < 2; ++kk)
        bF[nh * 2 + i][kk] = ld_frag(&Bl[buf][R * 64 + ((kk * 32 + l4 * 8) ^ ((R & 7) << 3))]);
    }
  };
  auto mm = [&](int mh, int nh) {
    __builtin_amdgcn_s_setprio(1);
    #pragma unroll
    for (int kk = 0; kk < 2; ++kk)        // kk outermost: 8 indep MFMAs/chunk
      #pragma unroll
      for (int i = 0; i < 4; ++i)
        #pragma unroll
        for (int ii = 0; ii < 2; ++ii)
          acc[mh * 4 + i][nh * 2 + ii] = __builtin_amdgcn_mfma_f32_16x16x32_bf16(
              aF[i][kk], bF[nh * 2 + ii][kk], acc[mh * 4 + i][nh * 2 + ii], 0, 0, 0);
    __builtin_amdgcn_s_setprio(0);
  };

  sp_a0b0(0); sp_b1a1(0); sp_a0b0(1);
  asm volatile("s_waitcnt vmcnt(4)" ::: "memory");
  __builtin_amdgcn_s_barrier();

  for (int J = 0; J < NT; ++J) {
    const int buf = J & 1;
    ldA(buf, 0);
    ldB(buf, 0);
    if (J + 1 < NT) sp_b1a1(J + 1);
    __builtin_amdgcn_s_barrier();
    asm volatile("s_waitcnt lgkmcnt(0)" ::: "memory");
    mm(0, 0);
    __builtin_amdgcn_s_barrier();
    ldB(buf, 1);
    __builtin_amdgcn_s_barrier();
    asm volatile("s_waitcnt lgkmcnt(0)" ::: "memory");
    mm(0, 1);
    __builtin_amdgcn_s_barrier();
    ldA(buf, 1);
    __builtin_amdgcn_s_barrier();
    asm volatile("s_waitcnt lgkmcnt(0)" ::: "memory");
    mm(1, 0);
    __builtin_amdgcn_s_barrier();
    if (J + 2 < NT) sp_a0b0(J + 2);
    asm volatile("s_waitcnt vmcnt(4)" ::: "memory");
    __builtin_amdgcn_s_barrier();
    mm(1, 1);
    __builtin_amdgcn_s_barrier();
  }

  if constexpr (EPI == 0) {
    #pragma unroll
    for (int mi = 0; mi < 8; ++mi)
      #pragma unroll
      for (int ni = 0; ni < 4; ++ni) {
        float v[4] = { acc[mi][ni][0], acc[mi][ni][1], acc[mi][ni][2], acc[mi][ni][3] };
        float o[4];
        xpose4(v, o, lane);
        const int colb = n0 + wc * 64 + ni * 16 + (l15 & ~3);
        const int row = m0 + wr * 128 + mi * 16 + l4 * 4 + (l15 & 3);
        float4 f4 = make_float4(o[0], o[1], o[2], o[3]);
        *reinterpret_cast<float4*>(&C[(size_t)row * N + colb]) = f4;
      }
  } else {
    #pragma unroll
    for (int ni = 0; ni < 4; ++ni) {
      const int col = n0 + wc * 64 + ni * 16 + l15;
      const int t2 = col >> 11;                 // wave-uniform (16-col blocks)
      #pragma unroll
      for (int mi = 0; mi < 8; ++mi) {
        const int row0 = m0 + wr * 128 + mi * 16 + l4 * 4;
        const int b = row0 >> 11, s0 = row0 & 2047;
        if (t2 == 2) {
          // vt [hb][d][s]: per-lane j-contiguous s -> packed 8B (original)
          const int h = (col >> 7) & 15, d = col & 127;
          bf16x4 v4 = { (__bf16)acc[mi][ni][0], (__bf16)acc[mi][ni][1],
                        (__bf16)acc[mi][ni][2], (__bf16)acc[mi][ni][3] };
          *reinterpret_cast<uintx2*>(&vtb[(((size_t)(h * 4 + b)) * 128 + d) * 2048 + s0]) =
              __builtin_bit_cast(uintx2, v4);
        } else {
          // q/k [hb][s][128]: 4x4 transpose -> packed 8B along d
          float v[4] = { acc[mi][ni][0], acc[mi][ni][1], acc[mi][ni][2], acc[mi][ni][3] };
          float o[4];
          xpose4(v, o, lane);
          const int colb = (col & ~3);
          const int h = (colb >> 7) & 15, d = colb & 127;
          const int s = s0 + (l15 & 3);
          unsigned short* base = t2 ? kb : qb;
          bf16x4 v4 = { (__bf16)o[0], (__bf16)o[1], (__bf16)o[2], (__bf16)o[3] };
          *reinterpret_cast<uintx2*>(&base[(((size_t)(h * 4 + b)) * 2048 + s) * 128 + d]) =
              __builtin_bit_cast(uintx2, v4);
        }
      }
    }
  }
}

// ---------------------------------------------------------------------------
// Causal flash attention, SWAPPED-OPERAND in-register softmax, FUSED RoPE,
// DOUBLE-BUFFERED K/V LDS (1 barrier/tile; commit targets idle buffer).
// q,k: [hb][s][128] bf16 (un-roped); vt: [hb][d][s] bf16.
// Output a: [b*2048+s][h*128+d] bf16. QBLK=256 (16 waves x 16 q), KBLK=64.
__global__ __launch_bounds__(1024)
void attn_kernel(const unsigned short* __restrict__ q,
                 const unsigned short* __restrict__ k,
                 const unsigned short* __restrict__ vt,
                 unsigned short* __restrict__ a,
                 const float2* __restrict__ tab) {
  const int hb = blockIdx.x;            // h*4 + b
  const int h = hb >> 2, b = hb & 3;
  const int Q = 7 - blockIdx.y;         // heavy blocks first
  const int q0 = Q * 256;
  const int tid = threadIdx.x, w = tid >> 6, lane = tid & 63;
  const int l15 = lane & 15, l4 = lane >> 4;

  __shared__ unsigned short Klds[2][64 * 128]; // XOR-swizzled rows, 2x16 KB
  __shared__ unsigned short Vlds[2][128 * 64]; // vt tile, swizzled, 2x16 KB

  const size_t qkbase = (size_t)hb * 2048 * 128;
  const size_t vtbase = (size_t)hb * 128 * 2048;
  const int qw_min = q0 + w * 16;
  const int qg = qw_min + l15;                // this lane's q row
  const float scale = 0.08838834764831845f;   // 1/sqrt(128)
  const int nt = 4 * Q + 4;

  // Q load + in-register rope: qf[ks] holds d = ks*32 + l4*8 .. +8 of row qg
  bf16x8 qf[4];
  #pragma unroll
  for (int ks = 0; ks < 4; ++ks) {
    union { uintx4 u; unsigned short sh[8]; } v;
    v.u = *reinterpret_cast<const uintx4*>(&q[qkbase + (size_t)qg * 128 + ks * 32 + l4 * 8]);
    const int i0 = qg * 64 + ks * 16 + l4 * 4;
    float4 c0 = *reinterpret_cast<const float4*>(&tab[i0]);
    float4 c1 = *reinterpret_cast<const float4*>(&tab[i0 + 2]);
    rope8(v.sh, c0, c1);
    qf[ks] = __builtin_bit_cast(bf16x8, v.u);
  }

  uintx4 kreg, vreg;
  float4 kcs0, kcs1;
  auto issue = [&](int kt) {
    kreg = *reinterpret_cast<const uintx4*>(
        &k[qkbase + (size_t)(kt + (tid >> 4)) * 128 + (tid & 15) * 8]);
    vreg = *reinterpret_cast<const uintx4*>(
        &vt[vtbase + (size_t)(tid >> 3) * 2048 + kt + (tid & 7) * 8]);
    const int i0 = (kt + (tid >> 4)) * 64 + (tid & 15) * 4;
    kcs0 = *reinterpret_cast<const float4*>(&tab[i0]);
    kcs1 = *reinterpret_cast<const float4*>(&tab[i0 + 2]);
  };
  auto commit = [&](int buf) {
    union { uintx4 u; unsigned short sh[8]; } kv;
    kv.u = kreg;
    rope8(kv.sh, kcs0, kcs1);           // K rope in-register
    const int kr = tid >> 4, kc = (tid & 15) * 8;
    *reinterpret_cast<uintx4*>(&Klds[buf][kr * 128 + (kc ^ ((kr & 7) << 3))]) = kv.u;
    const int vr = tid >> 3, vc = (tid & 7) * 8;
    *reinterpret_cast<uintx4*>(&Vlds[buf][vr * 64 + (vc ^ ((vr & 7) << 3))]) = vreg;
  };

  float m = -1e30f, lsum = 0.f;
  f32x4 acco[8];
  const f32x4 z = {0.f, 0.f, 0.f, 0.f};
  #pragma unroll
  for (int d2 = 0; d2 < 8; ++d2) acco[d2] = z;

  const int srcA = l15 + ((lane & 16) << 1);  // l15 + 32*(l4&1)
  const bool chi = (lane & 32) != 0;          // upper half of l4 groups

  issue(0);
  commit(0);
  __syncthreads();

  for (int t = 0; t < nt; ++t) {
    const int kt = t * 64;
    const int buf = t & 1;
    if (t + 1 < nt) issue(kt + 64);     // prefetch next tile under compute

    // S^T = K @ Q^T (swapped): lane holds q=l15, kv = c*16 + l4*4 + j
    f32x4 sc[4];
    #pragma unroll
    for (int c = 0; c < 4; ++c) sc[c] = z;
    __builtin_amdgcn_s_setprio(1);
    #pragma unroll
    for (int c = 0; c < 4; ++c) {
      const int kr = c * 16 + l15;
      #pragma unroll
      for (int ks = 0; ks < 4; ++ks) {
        bf16x8 kf = ld_frag(&Klds[buf][kr * 128 + ((l4 * 8 + ks * 32) ^ ((kr & 7) << 3))]);
        sc[c] = __builtin_amdgcn_mfma_f32_16x16x32_bf16(kf, qf[ks], sc[c], 0, 0, 0);
      }
    }
    __builtin_amdgcn_s_setprio(0);

    // scale + causal mask + in-lane max
    float mx = -1e30f;
    #pragma unroll
    for (int c = 0; c < 4; ++c) {
      const int kv0 = kt + c * 16 + l4 * 4;
      #pragma unroll
      for (int j = 0; j < 4; ++j) {
        float s = sc[c][j] * scale;
        s = (kv0 + j > qg) ? -1e30f : s;
        sc[c][j] = s;
        mx = fmaxf(mx, s);
      }
    }
    mx = fmaxf(mx, __shfl_xor(mx, 16));
    mx = fmaxf(mx, __shfl_xor(mx, 32));
    // defer-max (THR=8)
    if (__any(mx > m + 8.0f)) {
      float nm = fmaxf(m, mx);
      float al = __expf(m - nm);
      m = nm;
      lsum *= al;
      #pragma unroll
      for (int d2 = 0; d2 < 8; ++d2)
        #pragma unroll
        for (int j = 0; j < 4; ++j) acco[d2][j] *= al;
    }
    float rs = 0.f;
    #pragma unroll
    for (int c = 0; c < 4; ++c)
      #pragma unroll
      for (int j = 0; j < 4; ++j) {
        float pv = __expf(sc[c][j] - m);
        sc[c][j] = pv;
        rs += pv;
      }
    rs += __shfl_xor(rs, 16);
    rs += __shfl_xor(rs, 32);
    lsum += rs;

    // pack P to bf16 pairs: pk[c][half] = (p[c][2h], p[c][2h+1])
    unsigned int pk0[4], pk1[4];
    #pragma unroll
    for (int c = 0; c < 4; ++c) {
      pk0[c] = (unsigned)f2bf(sc[c][0]) | ((unsigned)f2bf(sc[c][1]) << 16);
      pk1[c] = (unsigned)f2bf(sc[c][2]) | ((unsigned)f2bf(sc[c][3]) << 16);
    }

    // O^T += V^T @ P^T ; P^T frag assembled via cross-group shfl
    __builtin_amdgcn_s_setprio(1);
    #pragma unroll
    for (int g = 0; g < 2; ++g) {
      const int ca = 2 * g, cb = 2 * g + 1;
      unsigned a0 = (unsigned)__shfl((int)pk0[ca], srcA);
      unsigned a1 = (unsigned)__shfl((int)pk1[ca], srcA);
      unsigned b0 = (unsigned)__shfl((int)pk0[cb], srcA);
      unsigned b1 = (unsigned)__shfl((int)pk1[cb], srcA);
      unsigned c0 = (unsigned)__shfl((int)pk0[ca], srcA + 16);
      unsigned c1 = (unsigned)__shfl((int)pk1[ca], srcA + 16);
      unsigned d0 = (unsigned)__shfl((int)pk0[cb], srcA + 16);
      unsigned d1 = (unsigned)__shfl((int)pk1[cb], srcA + 16);
      uintx4 u;
      u[0] = chi ? b0 : a0;
      u[1] = chi ? b1 : a1;
      u[2] = chi ? d0 : c0;
      u[3] = chi ? d1 : c1;
      bf16x8 pt = __builtin_bit_cast(bf16x8, u);
      #pragma unroll
      for (int d2 = 0; d2 < 8; ++d2) {
        const int dr = d2 * 16 + l15;
        bf16x8 vf = ld_frag(&Vlds[buf][dr * 64 + ((g * 32 + l4 * 8) ^ ((dr & 7) << 3))]);
        acco[d2] = __builtin_amdgcn_mfma_f32_16x16x32_bf16(vf, pt, acco[d2], 0, 0, 0);
      }
    }
    __builtin_amdgcn_s_setprio(0);

    if (t + 1 < nt) {
      commit(buf ^ 1);                  // write idle buffer (waits vmcnt)
      __syncthreads();                  // single barrier per tile
    }
  }

  // normalize + write a[b*2048+s][h*128+d] bf16; d = d2*16 + l4*4 + j
  const float inv = 1.0f / lsum;
  const size_t abase = ((size_t)(b * 2048 + qg)) * 2048 + h * 128 + l4 * 4;
  #pragma unroll
  for (int d2 = 0; d2 < 8; ++d2) {
    bf16x4 v4 = { (__bf16)(acco[d2][0] * inv), (__bf16)(acco[d2][1] * inv),
                  (__bf16)(acco[d2][2] * inv), (__bf16)(acco[d2][3] * inv) };
    *reinterpret_cast<uintx2*>(&a[abase + d2 * 16]) = __builtin_bit_cast(uintx2, v4);
  }
}

// ---------------------------------------------------------------------------
extern "C" void kernel_launch(void* const* d_in, const int* in_sizes, int n_in,
                              void* d_out, int out_size, void* d_ws, size_t ws_size,
                              hipStream_t stream) {
  const float* x = (const float*)d_in[0];
  const float* wqkv = (const float*)d_in[1];
  const float* wout = (const float*)d_in[2];
  float* out = (float*)d_out;
  char* ws = (char*)d_ws;
  char* ob = (char*)d_out;

  // ws (128 MiB): q, k, vt, a  (w_out bf16 reuses dead q region at the end)
  unsigned short* qbuf = (unsigned short*)(ws + 0);
  unsigned short* kbuf = (unsigned short*)(ws + 33554432);
  unsigned short* vtb  = (unsigned short*)(ws + 67108864);
  unsigned short* abuf = (unsigned short*)(ws + 100663296);
  unsigned short* woutb = qbuf;  // converted AFTER attn (q dead by then)
  // d_out (64 MB) as scratch until the final GEMM overwrites it:
  unsigned short* xb    = (unsigned short*)(ob + 0);          // 33.5 MB
  unsigned short* wqkvb = (unsigned short*)(ob + 33554432);   // 25.2 MB
  float2*         tab   = (float2*)(ob + 58720256);           // 1 MB

  hipLaunchKernelGGL(prep, dim3(14848), dim3(256), 0, stream,
                     x, xb, wqkv, wqkvb, tab);
  // QKV projection: q,k (un-roped) -> [hb][s][d]; V transposed -> vt [hb][d][s]
  hipLaunchKernelGGL((gemm8<1>), dim3(768), dim3(512), 0, stream,
                     xb, wqkvb, nullptr, qbuf, kbuf, vtb, 8192, 6144, 2048, 24);
  hipLaunchKernelGGL(attn_kernel, dim3(64, 8), dim3(1024), 0, stream,
                     qbuf, kbuf, vtb, abuf, (const float2*)tab);
  hipLaunchKernelGGL(cvt_bf16, dim3(2048), dim3(256), 0, stream, wout, woutb, 524288);
  hipLaunchKernelGGL((gemm8<0>), dim3(256), dim3(512), 0, stream,
                     abuf, woutb, out, nullptr, nullptr, nullptr,
                     8192, 2048, 2048, 8);
}

// Round 15
// 444.193 us; speedup vs baseline: 1.0250x; 1.0250x over previous
//
#include <hip/hip_runtime.h>
#include <hip/hip_bf16.h>

typedef __attribute__((ext_vector_type(8))) __bf16 bf16x8;
typedef __attribute__((ext_vector_type(4))) __bf16 bf16x4;
typedef __attribute__((ext_vector_type(4))) float f32x4;
typedef __attribute__((ext_vector_type(4))) unsigned int uintx4;
typedef __attribute__((ext_vector_type(2))) unsigned int uintx2;

__device__ __forceinline__ unsigned short f2bf(float f) {
  __bf16 h = (__bf16)f;
  return __builtin_bit_cast(unsigned short, h);
}
__device__ __forceinline__ float bf2f(unsigned short u) {
  unsigned int x = ((unsigned int)u) << 16;
  return __builtin_bit_cast(float, x);
}
__device__ __forceinline__ bf16x8 ld_frag(const unsigned short* p) {
  return __builtin_bit_cast(bf16x8, *reinterpret_cast<const uintx4*>(p));
}
__device__ __forceinline__ uintx2 cvt4(float4 v) {
  bf16x4 h = { (__bf16)v.x, (__bf16)v.y, (__bf16)v.z, (__bf16)v.w };
  return __builtin_bit_cast(uintx2, h);
}
// async global->LDS, 16B per lane; lds dest must be wave-uniform base
__device__ __forceinline__ void gload16(const unsigned short* g, unsigned short* l) {
  __builtin_amdgcn_global_load_lds(
      (const __attribute__((address_space(1))) void*)g,
      (__attribute__((address_space(3))) void*)l, 16, 0, 0);
}

__device__ __forceinline__ void cvt8(const float* in, unsigned short* out, int gid) {
  const float4* p = reinterpret_cast<const float4*>(in) + (size_t)gid * 2;
  float4 a = p[0], b = p[1];
  uintx2 lo = cvt4(a), hi = cvt4(b);
  uintx4 o = { lo[0], lo[1], hi[0], hi[1] };
  *(reinterpret_cast<uintx4*>(out) + gid) = o;
}

// rope 4 adjacent (even,odd) pairs held in 8 bf16 shorts; cs packed as
// (cos_i, sin_i, cos_{i+1}, sin_{i+1}) float4s
__device__ __forceinline__ void rope8(unsigned short* sh, float4 c0, float4 c1) {
  const float cs[4] = { c0.x, c0.z, c1.x, c1.z };
  const float sn[4] = { c0.y, c0.w, c1.y, c1.w };
  #pragma unroll
  for (int p = 0; p < 4; ++p) {
    float x1 = bf2f(sh[2 * p]), x2 = bf2f(sh[2 * p + 1]);
    sh[2 * p]     = f2bf(x1 * cs[p] - x2 * sn[p]);
    sh[2 * p + 1] = f2bf(x1 * sn[p] + x2 * cs[p]);
  }
}

// ---------------------------------------------------------------------------
// Fused prep: cvt x (8192 blocks) + cvt w_qkv (6144 blocks) + rope table (512)
__global__ __launch_bounds__(256)
void prep(const float* __restrict__ x, unsigned short* __restrict__ xb,
          const float* __restrict__ wqkv, unsigned short* __restrict__ wqkvb,
          float2* __restrict__ tab) {
  const int bid = blockIdx.x, tid = threadIdx.x;
  if (bid < 8192) {
    cvt8(x, xb, bid * 256 + tid);
  } else if (bid < 14336) {
    cvt8(wqkv, wqkvb, (bid - 8192) * 256 + tid);
  } else {
    int gid = (bid - 14336) * 256 + tid;   // 131072 total
    int i = gid & 63, s = gid >> 6;
    double inv = pow(10000.0, -(double)i / 64.0);
    double ang = (double)s * inv;
    tab[gid] = make_float2((float)cos(ang), (float)sin(ang));
  }
}

// fp32 -> bf16 bulk convert, 8 elems/thread
__global__ __launch_bounds__(256)
void cvt_bf16(const float* __restrict__ in, unsigned short* __restrict__ out, int n8) {
  int gid = blockIdx.x * 256 + threadIdx.x;
  if (gid >= n8) return;
  cvt8(in, out, gid);
}

// ---------------------------------------------------------------------------
// 8-phase GEMM C[M][N] = A[M][K] @ B[N][K]^T, bf16 in (R8-proven map, 888 TF).
// BM=BN=256, BK=64, 512 thr (8 waves 2Mx4N), per-wave 128x64 out.
// Bijective XCD swizzle (nwg % 8 == 0).
template<int EPI>
__global__ __launch_bounds__(512, 1)
void gemm8(const unsigned short* __restrict__ A, const unsigned short* __restrict__ B,
           float* __restrict__ C, unsigned short* __restrict__ qb,
           unsigned short* __restrict__ kb, unsigned short* __restrict__ vtb,
           int M, int N, int K, int nbx) {
  __shared__ unsigned short Al[2][256 * 64];   // 64 KiB
  __shared__ unsigned short Bl[2][256 * 64];   // 64 KiB
  const int nwg = gridDim.x, bid = blockIdx.x;
  const int swz = (bid & 7) * (nwg >> 3) + (bid >> 3);
  const int n0 = (swz % nbx) * 256, m0 = (swz / nbx) * 256;
  const int tid = threadIdx.x, lane = tid & 63, w = tid >> 6;
  const int wr = w >> 2, wc = w & 3, l15 = lane & 15, l4 = lane >> 4;
  const int NT = K >> 6;

  auto stage_half = [&](const unsigned short* src, int gr0, unsigned short* ldsb, int kt) {
    #pragma unroll
    for (int i = 0; i < 2; ++i) {
      const int rb = (w * 2 + i) * 8;                 // wave-uniform row base
      const int R = rb + (lane >> 3);
      const int cs = ((lane & 7) * 8) ^ ((R & 7) << 3);  // pre-swizzled src col
      gload16(&src[(size_t)(gr0 + R) * K + kt + cs], &ldsb[rb * 64]);
    }
  };
  auto sp_a0b0 = [&](int J) {   // halves {Am0, Bn0} of tile J
    const int buf = J & 1, kt = J * 64;
    stage_half(A, m0, &Al[buf][0], kt);
    stage_half(B, n0, &Bl[buf][0], kt);
  };
  auto sp_b1a1 = [&](int J) {   // halves {Bn1, Am1} of tile J
    const int buf = J & 1, kt = J * 64;
    stage_half(B, n0 + 128, &Bl[buf][128 * 64], kt);
    stage_half(A, m0 + 128, &Al[buf][128 * 64], kt);
  };

  f32x4 acc[8][4];
  const f32x4 z = {0.f, 0.f, 0.f, 0.f};
  #pragma unroll
  for (int mi = 0; mi < 8; ++mi)
    #pragma unroll
    for (int ni = 0; ni < 4; ++ni) acc[mi][ni] = z;

  bf16x8 aF[4][2], bF[4][2];
  auto ldA = [&](int buf, int mh) {
    #pragma unroll
    for (int i = 0; i < 4; ++i) {
      const int R = wr * 128 + (mh * 4 + i) * 16 + l15;
      #pragma unroll
      for (int kk = 0; kk < 2; ++kk)
        aF[i][kk] = ld_frag(&Al[buf][R * 64 + ((kk * 32 + l4 * 8) ^ ((R & 7) << 3))]);
    }
  };
  auto ldB = [&](int buf, int nh) {
    #pragma unroll
    for (int i = 0; i < 2; ++i) {
      const int R = wc * 64 + (nh * 2 + i) * 16 + l15;
      #pragma unroll
      for (int kk = 0; kk < 2; ++kk)
        bF[nh * 2 + i][kk] = ld_frag(&Bl[buf][R * 64 + ((kk * 32 + l4 * 8) ^ ((R & 7) << 3))]);
    }
  };
  auto mm = [&](int mh, int nh) {
    __builtin_amdgcn_s_setprio(1);
    #pragma unroll
    for (int kk = 0; kk < 2; ++kk)
      #pragma unroll
      for (int i = 0; i < 4; ++i)
        #pragma unroll
        for (int ii = 0; ii < 2; ++ii)
          acc[mh * 4 + i][nh * 2 + ii] = __builtin_amdgcn_mfma_f32_16x16x32_bf16(
              aF[i][kk], bF[nh * 2 + ii][kk], acc[mh * 4 + i][nh * 2 + ii], 0, 0, 0);
    __builtin_amdgcn_s_setprio(0);
  };

  sp_a0b0(0); sp_b1a1(0); sp_a0b0(1);
  asm volatile("s_waitcnt vmcnt(4)" ::: "memory");
  __builtin_amdgcn_s_barrier();

  for (int J = 0; J < NT; ++J) {
    const int buf = J & 1;
    ldA(buf, 0);
    ldB(buf, 0);
    if (J + 1 < NT) sp_b1a1(J + 1);
    __builtin_amdgcn_s_barrier();
    asm volatile("s_waitcnt lgkmcnt(0)" ::: "memory");
    mm(0, 0);
    __builtin_amdgcn_s_barrier();
    ldB(buf, 1);
    __builtin_amdgcn_s_barrier();
    asm volatile("s_waitcnt lgkmcnt(0)" ::: "memory");
    mm(0, 1);
    __builtin_amdgcn_s_barrier();
    ldA(buf, 1);
    __builtin_amdgcn_s_barrier();
    asm volatile("s_waitcnt lgkmcnt(0)" ::: "memory");
    mm(1, 0);
    __builtin_amdgcn_s_barrier();
    if (J + 2 < NT) sp_a0b0(J + 2);
    asm volatile("s_waitcnt vmcnt(4)" ::: "memory");
    __builtin_amdgcn_s_barrier();
    mm(1, 1);
    __builtin_amdgcn_s_barrier();
  }

  if constexpr (EPI == 0) {
    #pragma unroll
    for (int mi = 0; mi < 8; ++mi)
      #pragma unroll
      for (int ni = 0; ni < 4; ++ni) {
        const int col = n0 + wc * 64 + ni * 16 + l15;
        #pragma unroll
        for (int j = 0; j < 4; ++j) {
          const int row = m0 + wr * 128 + mi * 16 + l4 * 4 + j;
          C[(size_t)row * N + col] = acc[mi][ni][j];
        }
      }
  } else {
    #pragma unroll
    for (int ni = 0; ni < 4; ++ni) {
      const int col = n0 + wc * 64 + ni * 16 + l15;
      const int t2 = col >> 11, h = (col >> 7) & 15, d = col & 127;
      #pragma unroll
      for (int mi = 0; mi < 8; ++mi) {
        const int row0 = m0 + wr * 128 + mi * 16 + l4 * 4;
        const int b = row0 >> 11, s0 = row0 & 2047;
        if (t2 == 2) {
          bf16x4 v4 = { (__bf16)acc[mi][ni][0], (__bf16)acc[mi][ni][1],
                        (__bf16)acc[mi][ni][2], (__bf16)acc[mi][ni][3] };
          *reinterpret_cast<uintx2*>(&vtb[(((size_t)(h * 4 + b)) * 128 + d) * 2048 + s0]) =
              __builtin_bit_cast(uintx2, v4);
        } else {
          unsigned short* base = t2 ? kb : qb;
          #pragma unroll
          for (int j = 0; j < 4; ++j)
            base[(((size_t)(h * 4 + b)) * 2048 + s0 + j) * 128 + d] = f2bf(acc[mi][ni][j]);
        }
      }
    }
  }
}

// ---------------------------------------------------------------------------
// Causal flash attention, SWAPPED-OPERAND in-register softmax, FUSED RoPE,
// DOUBLE-BUFFERED K/V LDS (1 barrier/tile; commit targets idle buffer).
// q,k: [hb][s][128] bf16 (un-roped); vt: [hb][d][s] bf16.
// Output a: [b*2048+s][h*128+d] bf16. QBLK=256 (16 waves x 16 q), KBLK=64.
__global__ __launch_bounds__(1024)
void attn_kernel(const unsigned short* __restrict__ q,
                 const unsigned short* __restrict__ k,
                 const unsigned short* __restrict__ vt,
                 unsigned short* __restrict__ a,
                 const float2* __restrict__ tab) {
  const int hb = blockIdx.x;            // h*4 + b
  const int h = hb >> 2, b = hb & 3;
  const int Q = 7 - blockIdx.y;         // heavy blocks first
  const int q0 = Q * 256;
  const int tid = threadIdx.x, w = tid >> 6, lane = tid & 63;
  const int l15 = lane & 15, l4 = lane >> 4;

  __shared__ unsigned short Klds[2][64 * 128]; // XOR-swizzled rows, 2x16 KB
  __shared__ unsigned short Vlds[2][128 * 64]; // vt tile, swizzled, 2x16 KB

  const size_t qkbase = (size_t)hb * 2048 * 128;
  const size_t vtbase = (size_t)hb * 128 * 2048;
  const int qw_min = q0 + w * 16;
  const int qg = qw_min + l15;                // this lane's q row
  const float scale = 0.08838834764831845f;   // 1/sqrt(128)
  const int nt = 4 * Q + 4;

  // Q load + in-register rope: qf[ks] holds d = ks*32 + l4*8 .. +8 of row qg
  bf16x8 qf[4];
  #pragma unroll
  for (int ks = 0; ks < 4; ++ks) {
    union { uintx4 u; unsigned short sh[8]; } v;
    v.u = *reinterpret_cast<const uintx4*>(&q[qkbase + (size_t)qg * 128 + ks * 32 + l4 * 8]);
    const int i0 = qg * 64 + ks * 16 + l4 * 4;
    float4 c0 = *reinterpret_cast<const float4*>(&tab[i0]);
    float4 c1 = *reinterpret_cast<const float4*>(&tab[i0 + 2]);
    rope8(v.sh, c0, c1);
    qf[ks] = __builtin_bit_cast(bf16x8, v.u);
  }

  uintx4 kreg, vreg;
  float4 kcs0, kcs1;
  auto issue = [&](int kt) {
    kreg = *reinterpret_cast<const uintx4*>(
        &k[qkbase + (size_t)(kt + (tid >> 4)) * 128 + (tid & 15) * 8]);
    vreg = *reinterpret_cast<const uintx4*>(
        &vt[vtbase + (size_t)(tid >> 3) * 2048 + kt + (tid & 7) * 8]);
    const int i0 = (kt + (tid >> 4)) * 64 + (tid & 15) * 4;
    kcs0 = *reinterpret_cast<const float4*>(&tab[i0]);
    kcs1 = *reinterpret_cast<const float4*>(&tab[i0 + 2]);
  };
  auto commit = [&](int buf) {
    union { uintx4 u; unsigned short sh[8]; } kv;
    kv.u = kreg;
    rope8(kv.sh, kcs0, kcs1);           // K rope in-register
    const int kr = tid >> 4, kc = (tid & 15) * 8;
    *reinterpret_cast<uintx4*>(&Klds[buf][kr * 128 + (kc ^ ((kr & 7) << 3))]) = kv.u;
    const int vr = tid >> 3, vc = (tid & 7) * 8;
    *reinterpret_cast<uintx4*>(&Vlds[buf][vr * 64 + (vc ^ ((vr & 7) << 3))]) = vreg;
  };

  float m = -1e30f, lsum = 0.f;
  f32x4 acco[8];
  const f32x4 z = {0.f, 0.f, 0.f, 0.f};
  #pragma unroll
  for (int d2 = 0; d2 < 8; ++d2) acco[d2] = z;

  const int srcA = l15 + ((lane & 16) << 1);  // l15 + 32*(l4&1)
  const bool chi = (lane & 32) != 0;          // upper half of l4 groups

  issue(0);
  commit(0);
  __syncthreads();

  for (int t = 0; t < nt; ++t) {
    const int kt = t * 64;
    const int buf = t & 1;
    if (t + 1 < nt) issue(kt + 64);     // prefetch next tile under compute

    // S^T = K @ Q^T (swapped): lane holds q=l15, kv = c*16 + l4*4 + j
    f32x4 sc[4];
    #pragma unroll
    for (int c = 0; c < 4; ++c) sc[c] = z;
    __builtin_amdgcn_s_setprio(1);
    #pragma unroll
    for (int c = 0; c < 4; ++c) {
      const int kr = c * 16 + l15;
      #pragma unroll
      for (int ks = 0; ks < 4; ++ks) {
        bf16x8 kf = ld_frag(&Klds[buf][kr * 128 + ((l4 * 8 + ks * 32) ^ ((kr & 7) << 3))]);
        sc[c] = __builtin_amdgcn_mfma_f32_16x16x32_bf16(kf, qf[ks], sc[c], 0, 0, 0);
      }
    }
    __builtin_amdgcn_s_setprio(0);

    // scale + causal mask + in-lane max
    float mx = -1e30f;
    #pragma unroll
    for (int c = 0; c < 4; ++c) {
      const int kv0 = kt + c * 16 + l4 * 4;
      #pragma unroll
      for (int j = 0; j < 4; ++j) {
        float s = sc[c][j] * scale;
        s = (kv0 + j > qg) ? -1e30f : s;
        sc[c][j] = s;
        mx = fmaxf(mx, s);
      }
    }
    mx = fmaxf(mx, __shfl_xor(mx, 16));
    mx = fmaxf(mx, __shfl_xor(mx, 32));
    // defer-max (THR=8)
    if (__any(mx > m + 8.0f)) {
      float nm = fmaxf(m, mx);
      float al = __expf(m - nm);
      m = nm;
      lsum *= al;
      #pragma unroll
      for (int d2 = 0; d2 < 8; ++d2)
        #pragma unroll
        for (int j = 0; j < 4; ++j) acco[d2][j] *= al;
    }
    float rs = 0.f;
    #pragma unroll
    for (int c = 0; c < 4; ++c)
      #pragma unroll
      for (int j = 0; j < 4; ++j) {
        float pv = __expf(sc[c][j] - m);
        sc[c][j] = pv;
        rs += pv;
      }
    rs += __shfl_xor(rs, 16);
    rs += __shfl_xor(rs, 32);
    lsum += rs;

    // pack P to bf16 pairs: pk[c][half] = (p[c][2h], p[c][2h+1])
    unsigned int pk0[4], pk1[4];
    #pragma unroll
    for (int c = 0; c < 4; ++c) {
      pk0[c] = (unsigned)f2bf(sc[c][0]) | ((unsigned)f2bf(sc[c][1]) << 16);
      pk1[c] = (unsigned)f2bf(sc[c][2]) | ((unsigned)f2bf(sc[c][3]) << 16);
    }

    // O^T += V^T @ P^T ; P^T frag assembled via cross-group shfl
    __builtin_amdgcn_s_setprio(1);
    #pragma unroll
    for (int g = 0; g < 2; ++g) {
      const int ca = 2 * g, cb = 2 * g + 1;
      unsigned a0 = (unsigned)__shfl((int)pk0[ca], srcA);
      unsigned a1 = (unsigned)__shfl((int)pk1[ca], srcA);
      unsigned b0 = (unsigned)__shfl((int)pk0[cb], srcA);
      unsigned b1 = (unsigned)__shfl((int)pk1[cb], srcA);
      unsigned c0 = (unsigned)__shfl((int)pk0[ca], srcA + 16);
      unsigned c1 = (unsigned)__shfl((int)pk1[ca], srcA + 16);
      unsigned d0 = (unsigned)__shfl((int)pk0[cb], srcA + 16);
      unsigned d1 = (unsigned)__shfl((int)pk1[cb], srcA + 16);
      uintx4 u;
      u[0] = chi ? b0 : a0;
      u[1] = chi ? b1 : a1;
      u[2] = chi ? d0 : c0;
      u[3] = chi ? d1 : c1;
      bf16x8 pt = __builtin_bit_cast(bf16x8, u);
      #pragma unroll
      for (int d2 = 0; d2 < 8; ++d2) {
        const int dr = d2 * 16 + l15;
        bf16x8 vf = ld_frag(&Vlds[buf][dr * 64 + ((g * 32 + l4 * 8) ^ ((dr & 7) << 3))]);
        acco[d2] = __builtin_amdgcn_mfma_f32_16x16x32_bf16(vf, pt, acco[d2], 0, 0, 0);
      }
    }
    __builtin_amdgcn_s_setprio(0);

    if (t + 1 < nt) {
      commit(buf ^ 1);                  // write idle buffer (waits vmcnt)
      __syncthreads();                  // single barrier per tile
    }
  }

  // normalize + write a[b*2048+s][h*128+d] bf16; d = d2*16 + l4*4 + j
  const float inv = 1.0f / lsum;
  const size_t abase = ((size_t)(b * 2048 + qg)) * 2048 + h * 128 + l4 * 4;
  #pragma unroll
  for (int d2 = 0; d2 < 8; ++d2) {
    bf16x4 v4 = { (__bf16)(acco[d2][0] * inv), (__bf16)(acco[d2][1] * inv),
                  (__bf16)(acco[d2][2] * inv), (__bf16)(acco[d2][3] * inv) };
    *reinterpret_cast<uintx2*>(&a[abase + d2 * 16]) = __builtin_bit_cast(uintx2, v4);
  }
}

// ---------------------------------------------------------------------------
extern "C" void kernel_launch(void* const* d_in, const int* in_sizes, int n_in,
                              void* d_out, int out_size, void* d_ws, size_t ws_size,
                              hipStream_t stream) {
  const float* x = (const float*)d_in[0];
  const float* wqkv = (const float*)d_in[1];
  const float* wout = (const float*)d_in[2];
  float* out = (float*)d_out;
  char* ws = (char*)d_ws;
  char* ob = (char*)d_out;

  // ws (128 MiB): q, k, vt, a  (w_out bf16 reuses dead q region at the end)
  unsigned short* qbuf = (unsigned short*)(ws + 0);
  unsigned short* kbuf = (unsigned short*)(ws + 33554432);
  unsigned short* vtb  = (unsigned short*)(ws + 67108864);
  unsigned short* abuf = (unsigned short*)(ws + 100663296);
  unsigned short* woutb = qbuf;  // converted AFTER attn (q dead by then)
  // d_out (64 MB) as scratch until the final GEMM overwrites it:
  unsigned short* xb    = (unsigned short*)(ob + 0);          // 33.5 MB
  unsigned short* wqkvb = (unsigned short*)(ob + 33554432);   // 25.2 MB
  float2*         tab   = (float2*)(ob + 58720256);           // 1 MB

  hipLaunchKernelGGL(prep, dim3(14848), dim3(256), 0, stream,
                     x, xb, wqkv, wqkvb, tab);
  // QKV projection: q,k (un-roped) -> [hb][s][d]; V transposed -> vt [hb][d][s]
  hipLaunchKernelGGL((gemm8<1>), dim3(768), dim3(512), 0, stream,
                     xb, wqkvb, nullptr, qbuf, kbuf, vtb, 8192, 6144, 2048, 24);
  hipLaunchKernelGGL(attn_kernel, dim3(64, 8), dim3(1024), 0, stream,
                     qbuf, kbuf, vtb, abuf, (const float2*)tab);
  hipLaunchKernelGGL(cvt_bf16, dim3(2048), dim3(256), 0, stream, wout, woutb, 524288);
  hipLaunchKernelGGL((gemm8<0>), dim3(256), dim3(512), 0, stream,
                     abuf, woutb, out, nullptr, nullptr, nullptr,
                     8192, 2048, 2048, 8);
}